// Round 16
// baseline (427.885 us; speedup 1.0000x reference)
//
#include <hip/hip_runtime.h>
#include <hip/hip_bf16.h>
#include <cstdint>

namespace {
constexpr int B  = 32;
constexpr int L  = 512;
constexpr int D  = 256;
constexpr int H  = 8;
constexpr int DV = 32;
constexpr int DFF = 2048;
constexpr int CONCAT = D * H * DV + D;   // 65792
constexpr int BH = B * H;                // 256
}

typedef __attribute__((ext_vector_type(8))) short bf16x8;
typedef __attribute__((ext_vector_type(4))) float f32x4;

static __device__ __forceinline__ unsigned short f2bf_bits(float x) {
    __hip_bfloat16 h = __float2bfloat16(x);
    return *reinterpret_cast<unsigned short*>(&h);
}
static __device__ __forceinline__ float bf2f(short u) {
    unsigned int x = ((unsigned int)(unsigned short)u) << 16;
    union { unsigned int u; float f; } c; c.u = x; return c.f;
}
static __device__ __forceinline__ bf16x8 pack8(const float* v) {
    bf16x8 r;
#pragma unroll
    for (int j = 0; j < 8; ++j) r[j] = (short)f2bf_bits(v[j]);
    return r;
}

// ---------------- fused prep v2 (r15) ----------------
__global__ __launch_bounds__(256) void prep_kernel(const int* __restrict__ amask,
                                                   unsigned int* __restrict__ mb,
                                                   const float* __restrict__ WQ,
                                                   const float* __restrict__ WK,
                                                   const float* __restrict__ WV,
                                                   __hip_bfloat16* __restrict__ WT,
                                                   const float* __restrict__ emb,
                                                   __hip_bfloat16* __restrict__ embT,
                                                   const int* __restrict__ imask,
                                                   float* __restrict__ avp,
                                                   float* __restrict__ avc) {
    __shared__ __hip_bfloat16 tile[32][264];
    __shared__ int mk[64];
    const int blk = blockIdx.x;
    const int t = threadIdx.x;

    if (blk < 32768) {                       // ---- maskpack
        const size_t gid = (size_t)blk * 256 + t;
        int v = amask[gid];
        unsigned long long bal = __ballot(v != 0);
        if ((t & 63) == 0) *reinterpret_cast<unsigned long long*>(mb + (gid >> 5)) = bal;
    } else if (blk < 33536) {                // ---- transW
        const int e = blk - 32768;
        const int mat = e >> 8, bx = e & 255;
        const int idx = bx * 256 + t;
        const int n = idx >> 8, k = idx & 255;
        const float* W = (mat == 0) ? WQ : (mat == 1) ? WK : WV;
        WT[(size_t)mat * 65536 + idx] = __float2bfloat16(W[(size_t)k * 256 + n]);
    } else if (blk < 34048) {                // ---- embtrans -> embT
        const int e = blk - 33536;
        const int lc = e & 15, b = e >> 4;
        const int l0 = lc * 32;
#pragma unroll 4
        for (int i = 0; i < 32; ++i)
            tile[i][t] = __float2bfloat16(emb[((size_t)b * 512 + l0 + i) * 256 + t]);
        __syncthreads();
        __hip_bfloat16* dst = embT + ((size_t)b * 256 + t) * 512 + l0;
#pragma unroll
        for (int i0 = 0; i0 < 32; i0 += 8) {
            bf16x8 v;
#pragma unroll
            for (int j = 0; j < 8; ++j) v[j] = *reinterpret_cast<short*>(&tile[i0 + j][t]);
            *reinterpret_cast<bf16x8*>(dst + i0) = v;
        }
    } else {                                 // ---- avg partials (2-stage preserved)
        const int bg = blk - 34048;
        const int b = bg >> 3, g = bg & 7;
        if (t < 64) mk[t] = imask[b * L + g * 64 + t];
        __syncthreads();
        float s = 0.f;
#pragma unroll 4
        for (int i = 0; i < 64; ++i)
            if (mk[i]) s += emb[((size_t)b * L + g * 64 + i) * 256 + t];
        avp[(size_t)bg * 256 + t] = s;
        if (t == 0) {
            int c = 0;
#pragma unroll
            for (int i = 0; i < 64; ++i) c += (mk[i] != 0);
            avc[bg] = (float)c;
        }
    }
}

__global__ __launch_bounds__(256) void avg_comb(const float* __restrict__ avp,
                                                const float* __restrict__ avc,
                                                __hip_bfloat16* __restrict__ xR) {
    const int b = blockIdx.x;
    const int t = threadIdx.x;
    float s = 0.f, c = 0.f;
#pragma unroll
    for (int g = 0; g < 8; ++g) {
        s += avp[(size_t)(b * 8 + g) * 256 + t];
        c += avc[b * 8 + g];
    }
    xR[(size_t)b * CONCAT + 65536 + t] = __float2bfloat16(s / fmaxf(c, 1.f));
}

// ---------------- QKV projection via MFMA (r15) ----------------
__global__ __launch_bounds__(256) void proj_mfma(const float* __restrict__ emb,
                                                 const __hip_bfloat16* __restrict__ WT,
                                                 __hip_bfloat16* __restrict__ Qb,
                                                 __hip_bfloat16* __restrict__ Kb,
                                                 __hip_bfloat16* __restrict__ Vt) {
    const int rb = blockIdx.x * 32;
    const int t = threadIdx.x;
    const int w = t >> 6, l = t & 63;
    const int lr = l & 15, lg = l >> 4;

    f32x4 accQ[2][4], accK[2][4], accV[2][4];
#pragma unroll
    for (int m = 0; m < 2; ++m)
#pragma unroll
        for (int n = 0; n < 4; ++n) {
            accQ[m][n] = (f32x4){0.f,0.f,0.f,0.f};
            accK[m][n] = (f32x4){0.f,0.f,0.f,0.f};
            accV[m][n] = (f32x4){0.f,0.f,0.f,0.f};
        }

    for (int kc = 0; kc < 8; ++kc) {
        const int k0 = kc * 32 + lg * 8;
        bf16x8 a[2];
#pragma unroll
        for (int m = 0; m < 2; ++m) {
            const float* ap = emb + (size_t)(rb + m * 16 + lr) * 256 + k0;
            float av[8];
#pragma unroll
            for (int j = 0; j < 8; ++j) av[j] = ap[j];
            a[m] = pack8(av);
        }
#pragma unroll
        for (int nt = 0; nt < 4; ++nt) {
            const int col = w * 64 + nt * 16 + lr;
            bf16x8 bq = *reinterpret_cast<const bf16x8*>(WT + (size_t)col * 256 + k0);
            bf16x8 bk = *reinterpret_cast<const bf16x8*>(WT + 65536 + (size_t)col * 256 + k0);
            bf16x8 bv = *reinterpret_cast<const bf16x8*>(WT + 131072 + (size_t)col * 256 + k0);
            accQ[0][nt] = __builtin_amdgcn_mfma_f32_16x16x32_bf16(a[0], bq, accQ[0][nt], 0, 0, 0);
            accQ[1][nt] = __builtin_amdgcn_mfma_f32_16x16x32_bf16(a[1], bq, accQ[1][nt], 0, 0, 0);
            accK[0][nt] = __builtin_amdgcn_mfma_f32_16x16x32_bf16(a[0], bk, accK[0][nt], 0, 0, 0);
            accK[1][nt] = __builtin_amdgcn_mfma_f32_16x16x32_bf16(a[1], bk, accK[1][nt], 0, 0, 0);
            accV[0][nt] = __builtin_amdgcn_mfma_f32_16x16x32_bf16(a[0], bv, accV[0][nt], 0, 0, 0);
            accV[1][nt] = __builtin_amdgcn_mfma_f32_16x16x32_bf16(a[1], bv, accV[1][nt], 0, 0, 0);
        }
    }

    const int b = rb >> 9, l0 = rb & 511;
#pragma unroll
    for (int m = 0; m < 2; ++m)
#pragma unroll
        for (int nt = 0; nt < 4; ++nt) {
            const int n = w * 64 + nt * 16 + lr;
            const int h = n >> 5, d = n & 31;
            const int bh = b * 8 + h;
#pragma unroll
            for (int r = 0; r < 4; ++r) {
                const int ll = l0 + m * 16 + lg * 4 + r;
                Qb[((size_t)bh * 512 + ll) * 32 + d] = __float2bfloat16(accQ[m][nt][r]);
                Kb[((size_t)bh * 512 + ll) * 32 + d] = __float2bfloat16(accK[m][nt][r]);
                Vt[((size_t)bh * 32 + d) * 512 + ll] = __float2bfloat16(accV[m][nt][r]);
            }
        }
}

// ---------------- MFMA attention v5: all P-chunks staged once, 3 barriers total ----------------
__global__ __launch_bounds__(256) void attn_mfma(const __hip_bfloat16* __restrict__ Q,
                                                 const __hip_bfloat16* __restrict__ K,
                                                 const __hip_bfloat16* __restrict__ Vt,
                                                 const unsigned int* __restrict__ mb,
                                                 float* __restrict__ attn_out,
                                                 float* __restrict__ ctx) {
    const int qt = blockIdx.x;
    const int bh = blockIdx.y;
    const int b = bh >> 3, h = bh & 7;
    const int t = threadIdx.x;
    const int w = t >> 6, l = t & 63;
    const int lr = l & 15, lg = l >> 4;
    const int q0 = qt * 16;

    __shared__ __hip_bfloat16 Pl[4][4][16][40];   // [wave][chunk][row][col(32)+pad]
    __shared__ float rmax[4][16];
    __shared__ float rsum[4][16];
    __shared__ float Ored[4][16][32];

    const float scale = 0.17677669529663687f;

    const bf16x8 aq = *reinterpret_cast<const bf16x8*>(Q + ((size_t)bh * L + q0 + lr) * 32 + lg * 8);
    const __hip_bfloat16* Kbase = K + (size_t)bh * L * 32;

    f32x4 sc[8];
#pragma unroll
    for (int kt = 0; kt < 8; ++kt) {
        bf16x8 bk = *reinterpret_cast<const bf16x8*>(
            Kbase + (size_t)((w * 8 + kt) * 16 + lr) * 32 + lg * 8);
        sc[kt] = __builtin_amdgcn_mfma_f32_16x16x32_bf16(aq, bk, (f32x4){0.f,0.f,0.f,0.f}, 0, 0, 0);
    }

    float tmp[4];
#pragma unroll
    for (int r = 0; r < 4; ++r) {
        const int q = q0 + lg * 4 + r;
        uint4 mw = *reinterpret_cast<const uint4*>(mb + ((size_t)b * L + q) * 16 + w * 4);
        const unsigned int wds[4] = {mw.x, mw.y, mw.z, mw.w};
        float m = -3.4e38f;
#pragma unroll
        for (int kt = 0; kt < 8; ++kt) {
            unsigned bit = (unsigned)lr + ((kt & 1) << 4);
            float s = ((wds[kt >> 1] >> bit) & 1u) ? -1e9f : sc[kt][r] * scale;
            sc[kt][r] = s;
            m = fmaxf(m, s);
        }
        m = fmaxf(m, __shfl_xor(m, 1));
        m = fmaxf(m, __shfl_xor(m, 2));
        m = fmaxf(m, __shfl_xor(m, 4));
        m = fmaxf(m, __shfl_xor(m, 8));
        tmp[r] = m;
    }
    if (lr == 0) {
#pragma unroll
        for (int r = 0; r < 4; ++r) rmax[w][lg * 4 + r] = tmp[r];
    }
    __syncthreads();                                   // barrier 1

#pragma unroll
    for (int r = 0; r < 4; ++r) {
        const int row = lg * 4 + r;
        const float gm = fmaxf(fmaxf(rmax[0][row], rmax[1][row]),
                               fmaxf(rmax[2][row], rmax[3][row]));
        float sum = 0.f;
#pragma unroll
        for (int kt = 0; kt < 8; ++kt) {
            float e = __expf(sc[kt][r] - gm);
            sc[kt][r] = e;
            sum += e;
        }
        sum += __shfl_xor(sum, 1);
        sum += __shfl_xor(sum, 2);
        sum += __shfl_xor(sum, 4);
        sum += __shfl_xor(sum, 8);
        tmp[r] = sum;
    }
    if (lr == 0) {
#pragma unroll
        for (int r = 0; r < 4; ++r) rsum[w][lg * 4 + r] = tmp[r];
    }

    // stage ALL four P-chunks (D->A transpose), then one barrier
#pragma unroll
    for (int cc = 0; cc < 4; ++cc)
#pragma unroll
        for (int r = 0; r < 4; ++r) {
            Pl[w][cc][lg * 4 + r][lr]      = __float2bfloat16(sc[2*cc  ][r]);
            Pl[w][cc][lg * 4 + r][16 + lr] = __float2bfloat16(sc[2*cc+1][r]);
        }
    __syncthreads();                                   // barrier 2 (covers rsum too)

    const float my_ri = 1.f / (rsum[0][lr] + rsum[1][lr] + rsum[2][lr] + rsum[3][lr]);

    f32x4 acc0 = {0.f,0.f,0.f,0.f}, acc1 = {0.f,0.f,0.f,0.f};
    const __hip_bfloat16* Vb = Vt + (size_t)bh * 32 * L;
    float* aob = attn_out + ((size_t)bh * L + q0 + lr) * L + w * 128;
#pragma unroll
    for (int cc = 0; cc < 4; ++cc) {
        bf16x8 ap = *reinterpret_cast<const bf16x8*>(&Pl[w][cc][lr][lg * 8]);
        float4 o0, o1;
        o0.x = bf2f(ap[0]) * my_ri; o0.y = bf2f(ap[1]) * my_ri;
        o0.z = bf2f(ap[2]) * my_ri; o0.w = bf2f(ap[3]) * my_ri;
        o1.x = bf2f(ap[4]) * my_ri; o1.y = bf2f(ap[5]) * my_ri;
        o1.z = bf2f(ap[6]) * my_ri; o1.w = bf2f(ap[7]) * my_ri;
        float* ao = aob + cc * 32 + lg * 8;
        *reinterpret_cast<float4*>(ao)     = o0;
        *reinterpret_cast<float4*>(ao + 4) = o1;
        bf16x8 bv0 = *reinterpret_cast<const bf16x8*>(Vb + (size_t)lr        * L + w * 128 + cc * 32 + lg * 8);
        bf16x8 bv1 = *reinterpret_cast<const bf16x8*>(Vb + (size_t)(16 + lr) * L + w * 128 + cc * 32 + lg * 8);
        acc0 = __builtin_amdgcn_mfma_f32_16x16x32_bf16(ap, bv0, acc0, 0, 0, 0);
        acc1 = __builtin_amdgcn_mfma_f32_16x16x32_bf16(ap, bv1, acc1, 0, 0, 0);
    }

#pragma unroll
    for (int r = 0; r < 4; ++r) {
        Ored[w][lg * 4 + r][lr]      = acc0[r];
        Ored[w][lg * 4 + r][16 + lr] = acc1[r];
    }
    __syncthreads();                                   // barrier 3
    for (int v = t; v < 512; v += 256) {
        const int row = v >> 5, col = v & 31;
        const float s = Ored[0][row][col] + Ored[1][row][col]
                      + Ored[2][row][col] + Ored[3][row][col];
        const float gs = rsum[0][row] + rsum[1][row] + rsum[2][row] + rsum[3][row];
        ctx[((size_t)b * L + q0 + row) * 256 + h * 32 + col] = s / gs;
    }
}

// ---------------- column softmax v2 (r14) ----------------
__global__ __launch_bounds__(256) void wts_kernel(const float* __restrict__ ctx,
                                                  const int* __restrict__ imask,
                                                  __hip_bfloat16* __restrict__ wtsT) {
    const int b = blockIdx.x >> 3;
    const int ct = blockIdx.x & 7;
    const int t = threadIdx.x;
    const int c = ct * 32 + (t & 31);
    const int g = t >> 5;
    __shared__ float rm[8][32];
    __shared__ float rs[8][32];
    __shared__ int mk[512];
    for (int p = t; p < 512; p += 256) mk[p] = imask[b * 512 + p];
    __syncthreads();

    float m = -3.4e38f;
    for (int ll = g; ll < 512; ll += 8) {
        float v = mk[ll] ? ctx[((size_t)b * 512 + ll) * 256 + c] : -1e9f;
        m = fmaxf(m, v);
    }
    rm[g][t & 31] = m;
    __syncthreads();
    float M = rm[0][t & 31];
#pragma unroll
    for (int q = 1; q < 8; ++q) M = fmaxf(M, rm[q][t & 31]);

    float sum = 0.f;
    for (int ll = g; ll < 512; ll += 8) {
        float v = mk[ll] ? ctx[((size_t)b * 512 + ll) * 256 + c] : -1e9f;
        sum += __expf(v - M);
    }
    rs[g][t & 31] = sum;
    __syncthreads();
    float S = 0.f;
#pragma unroll
    for (int q = 0; q < 8; ++q) S += rs[q][t & 31];
    const float rinv = 1.f / S;

    __hip_bfloat16* wrow = wtsT + ((size_t)b * 256 + c) * 512;
    for (int ll = g; ll < 512; ll += 8) {
        float v = mk[ll] ? ctx[((size_t)b * 512 + ll) * 256 + c] : -1e9f;
        wrow[ll] = __float2bfloat16(__expf(v - M) * rinv);
    }
}

// ---------------- pooled via MFMA (unchanged) ----------------
__global__ __launch_bounds__(256) void pooled_mfma(const __hip_bfloat16* __restrict__ embT,
                                                   const __hip_bfloat16* __restrict__ wtsT,
                                                   __hip_bfloat16* __restrict__ xR) {
    const int ct = blockIdx.x, dt = blockIdx.y, b = blockIdx.z;
    const int t = threadIdx.x;
    const int w = t >> 6, l = t & 63;
    const int lr = l & 15, lg = l >> 4;
    const int wr = w >> 1, wc = w & 1;
    const int d0 = dt * 64 + wr * 32;
    const int c0 = ct * 64 + wc * 32;

    f32x4 acc[2][2];
#pragma unroll
    for (int m = 0; m < 2; ++m)
#pragma unroll
        for (int n = 0; n < 2; ++n) acc[m][n] = (f32x4){0.f,0.f,0.f,0.f};

    for (int lc = 0; lc < 16; ++lc) {
        const int lbase = lc * 32 + lg * 8;
        bf16x8 a[2], bb[2];
#pragma unroll
        for (int m = 0; m < 2; ++m)
            a[m] = *reinterpret_cast<const bf16x8*>(
                embT + ((size_t)b * 256 + d0 + m * 16 + lr) * 512 + lbase);
#pragma unroll
        for (int n = 0; n < 2; ++n)
            bb[n] = *reinterpret_cast<const bf16x8*>(
                wtsT + ((size_t)b * 256 + c0 + n * 16 + lr) * 512 + lbase);
#pragma unroll
        for (int m = 0; m < 2; ++m)
#pragma unroll
            for (int n = 0; n < 2; ++n)
                acc[m][n] = __builtin_amdgcn_mfma_f32_16x16x32_bf16(a[m], bb[n], acc[m][n], 0, 0, 0);
    }
#pragma unroll
    for (int m = 0; m < 2; ++m)
#pragma unroll
        for (int n = 0; n < 2; ++n)
#pragma unroll
            for (int r = 0; r < 4; ++r) {
                const int d = d0 + m * 16 + lg * 4 + r;
                const int c = c0 + n * 16 + lr;
                xR[(size_t)b * CONCAT + d * 256 + c] = __float2bfloat16(acc[m][n][r]);
            }
}

// ---------------- fc via MFMA; CHUNK = K per kc slot; unroll 4 ----------------
template<int KSTEPS, int XSTRIDE, int CHUNK>
__global__ __launch_bounds__(256) void fc_mfma(const __hip_bfloat16* __restrict__ xR,
                                               const float* __restrict__ Wf,
                                               float* __restrict__ part,
                                               int kcbase) {
    const int bx = blockIdx.x;
    const int kc = blockIdx.y + kcbase;
    const int kbase = kc * CHUNK;
    const int t = threadIdx.x;
    const int w = t >> 6, l = t & 63;
    const int lr = l & 15, lg = l >> 4;
    const int col0 = bx * 256 + w * 64;

    f32x4 acc[2][4];
#pragma unroll
    for (int m = 0; m < 2; ++m)
#pragma unroll
        for (int n = 0; n < 4; ++n) acc[m][n] = (f32x4){0.f,0.f,0.f,0.f};

#pragma unroll 4
    for (int kt = 0; kt < KSTEPS; ++kt) {
        const int k = kbase + kt * 32 + lg * 8;
        bf16x8 a0 = *reinterpret_cast<const bf16x8*>(xR + (size_t)lr * XSTRIDE + k);
        bf16x8 a1 = *reinterpret_cast<const bf16x8*>(xR + (size_t)(16 + lr) * XSTRIDE + k);
#pragma unroll
        for (int nt = 0; nt < 4; ++nt) {
            const float* wp = Wf + (size_t)k * 2048 + col0 + nt * 16 + lr;
            float wv[8];
#pragma unroll
            for (int j = 0; j < 8; ++j) wv[j] = wp[(size_t)j * 2048];
            bf16x8 bw = pack8(wv);
            acc[0][nt] = __builtin_amdgcn_mfma_f32_16x16x32_bf16(a0, bw, acc[0][nt], 0, 0, 0);
            acc[1][nt] = __builtin_amdgcn_mfma_f32_16x16x32_bf16(a1, bw, acc[1][nt], 0, 0, 0);
        }
    }
    float* pp = part + (size_t)kc * 65536;
#pragma unroll
    for (int m = 0; m < 2; ++m)
#pragma unroll
        for (int nt = 0; nt < 4; ++nt)
#pragma unroll
            for (int r = 0; r < 4; ++r) {
                const int bb = m * 16 + lg * 4 + r;
                pp[(size_t)bb * 2048 + col0 + nt * 16 + lr] = acc[m][nt][r];
            }
}

// ---------------- fc1 reduce (r14) ----------------
__global__ __launch_bounds__(256) void fcreduce1(const float* __restrict__ part,
                                                 const float* __restrict__ bias,
                                                 __hip_bfloat16* __restrict__ outR) {
    const int t = threadIdx.x;
    const int o = blockIdx.x * 128 + (t & 127);
    const int half = t >> 7;
    __shared__ float red[128];
    float s = 0.f;
    if (half == 0) {
        for (int kc = 0; kc < 65; ++kc) s += part[(size_t)kc * 65536 + o];
    } else {
        for (int kc = 65; kc < 129; ++kc) s += part[(size_t)kc * 65536 + o];
    }
    if (half) red[t & 127] = s;
    __syncthreads();
    if (!half) {
        s += red[t];
        const int col = o & 2047;
        s = fmaxf(s + bias[col], 0.f);
        outR[o] = __float2bfloat16(s);
    }
}

// ---------------- fc23 (r14) ----------------
__global__ __launch_bounds__(256) void fc23_kernel(const float* __restrict__ part2,
                                                   const float* __restrict__ b2,
                                                   const float* __restrict__ w3,
                                                   const float* __restrict__ b3,
                                                   float* __restrict__ out) {
    const int b = blockIdx.x;
    const int t = threadIdx.x;
    float s = 0.f;
    for (int c = t; c < DFF; c += 256) {
        float v = 0.f;
#pragma unroll
        for (int kc = 0; kc < 16; ++kc) v += part2[(size_t)kc * 65536 + b * 2048 + c];
        v = fmaxf(v + b2[c], 0.f);
        s += v * w3[c];
    }
#pragma unroll
    for (int o = 1; o < 64; o <<= 1) s += __shfl_xor(s, o);
    __shared__ float red[4];
    if ((t & 63) == 0) red[t >> 6] = s;
    __syncthreads();
    if (t == 0) out[b] = red[0] + red[1] + red[2] + red[3] + b3[0];
}

extern "C" void kernel_launch(void* const* d_in, const int* in_sizes, int n_in,
                              void* d_out, int out_size, void* d_ws, size_t ws_size,
                              hipStream_t stream) {
    const float* emb   = (const float*)d_in[0];
    const int*   amask = (const int*)d_in[1];
    const int*   imask = (const int*)d_in[2];
    const float* WQ    = (const float*)d_in[3];
    const float* WK    = (const float*)d_in[4];
    const float* WV    = (const float*)d_in[5];
    const float* fc1w  = (const float*)d_in[6];
    const float* fc1b  = (const float*)d_in[7];
    const float* fc2w  = (const float*)d_in[8];
    const float* fc2b  = (const float*)d_in[9];
    const float* fc3w  = (const float*)d_in[10];
    const float* fc3b  = (const float*)d_in[11];

    float* out_head = (float*)d_out;
    float* attn_out = out_head + 32;

    float* ws = (float*)d_ws;
    const size_t OFF_XR   = 0;
    const size_t OFF_Q    = OFF_XR + 1052672;
    const size_t OFF_K    = OFF_Q + 2097152;
    const size_t OFF_V    = OFF_K + 2097152;
    const size_t OFF_CTX  = OFF_V + 2097152;
    const size_t OFF_WTST = OFF_CTX + 4194304;
    const size_t OFF_P1   = OFF_WTST + 2097152;
    const size_t OFF_H1   = OFF_P1 + 8454144;
    const size_t OFF_P2   = OFF_H1 + 32768;
    const size_t OFF_MB   = OFF_P2 + 1048576;
    const size_t OFF_AVP  = OFF_MB + 262144;
    const size_t OFF_EMBT = OFF_AVP + 65792;
    const size_t OFF_WT   = OFF_EMBT + 2097152;

    __hip_bfloat16* xR   = (__hip_bfloat16*)(ws + OFF_XR);
    __hip_bfloat16* Qb   = (__hip_bfloat16*)(ws + OFF_Q);
    __hip_bfloat16* Kb   = (__hip_bfloat16*)(ws + OFF_K);
    __hip_bfloat16* Vt   = (__hip_bfloat16*)(ws + OFF_V);
    float* ctx   = ws + OFF_CTX;
    __hip_bfloat16* wtsT = (__hip_bfloat16*)(ws + OFF_WTST);
    float* part1 = ws + OFF_P1;
    __hip_bfloat16* h1R  = (__hip_bfloat16*)(ws + OFF_H1);
    float* part2 = ws + OFF_P2;
    unsigned int* mbits = (unsigned int*)(ws + OFF_MB);
    float* avp   = ws + OFF_AVP;
    float* avc   = ws + OFF_AVP + 65536;
    __hip_bfloat16* embT = (__hip_bfloat16*)(ws + OFF_EMBT);
    __hip_bfloat16* WT   = (__hip_bfloat16*)(ws + OFF_WT);

    prep_kernel<<<dim3(34304), 256, 0, stream>>>(amask, mbits, WQ, WK, WV, WT,
                                                 emb, embT, imask, avp, avc);
    proj_mfma<<<dim3(512), 256, 0, stream>>>(emb, WT, Qb, Kb, Vt);
    attn_mfma<<<dim3(32, BH), 256, 0, stream>>>(Qb, Kb, Vt, mbits, attn_out, ctx);
    wts_kernel<<<dim3(B * 8), 256, 0, stream>>>(ctx, imask, wtsT);
    pooled_mfma<<<dim3(4, 4, B), 256, 0, stream>>>(embT, wtsT, xR);
    avg_comb<<<dim3(B), 256, 0, stream>>>(avp, avc, xR);

    fc_mfma<16, CONCAT, 512><<<dim3(8, 128), 256, 0, stream>>>(xR, fc1w, part1, 0);
    fc_mfma<8, CONCAT, 512><<<dim3(8, 1), 256, 0, stream>>>(xR, fc1w, part1, 128);
    fcreduce1<<<dim3(512), 256, 0, stream>>>(part1, fc1b, h1R);

    fc_mfma<4, DFF, 128><<<dim3(8, 16), 256, 0, stream>>>(h1R, fc2w, part2, 0);
    fc23_kernel<<<dim3(B), 256, 0, stream>>>(part2, fc2b, fc3w, fc3b, out_head);
}

// Round 17
// 423.006 us; speedup vs baseline: 1.0115x; 1.0115x over previous
//
#include <hip/hip_runtime.h>
#include <hip/hip_bf16.h>
#include <cstdint>

namespace {
constexpr int B  = 32;
constexpr int L  = 512;
constexpr int D  = 256;
constexpr int H  = 8;
constexpr int DV = 32;
constexpr int DFF = 2048;
constexpr int CONCAT = D * H * DV + D;   // 65792
constexpr int BH = B * H;                // 256
}

typedef __attribute__((ext_vector_type(8))) short bf16x8;
typedef __attribute__((ext_vector_type(4))) float f32x4;

static __device__ __forceinline__ unsigned short f2bf_bits(float x) {
    __hip_bfloat16 h = __float2bfloat16(x);
    return *reinterpret_cast<unsigned short*>(&h);
}
static __device__ __forceinline__ float bf2f(short u) {
    unsigned int x = ((unsigned int)(unsigned short)u) << 16;
    union { unsigned int u; float f; } c; c.u = x; return c.f;
}
static __device__ __forceinline__ bf16x8 pack8(const float* v) {
    bf16x8 r;
#pragma unroll
    for (int j = 0; j < 8; ++j) r[j] = (short)f2bf_bits(v[j]);
    return r;
}

// ---------------- fused prep v2 (r15) ----------------
__global__ __launch_bounds__(256) void prep_kernel(const int* __restrict__ amask,
                                                   unsigned int* __restrict__ mb,
                                                   const float* __restrict__ WQ,
                                                   const float* __restrict__ WK,
                                                   const float* __restrict__ WV,
                                                   __hip_bfloat16* __restrict__ WT,
                                                   const float* __restrict__ emb,
                                                   __hip_bfloat16* __restrict__ embT,
                                                   const int* __restrict__ imask,
                                                   float* __restrict__ avp,
                                                   float* __restrict__ avc) {
    __shared__ __hip_bfloat16 tile[32][264];
    __shared__ int mk[64];
    const int blk = blockIdx.x;
    const int t = threadIdx.x;

    if (blk < 32768) {                       // ---- maskpack
        const size_t gid = (size_t)blk * 256 + t;
        int v = amask[gid];
        unsigned long long bal = __ballot(v != 0);
        if ((t & 63) == 0) *reinterpret_cast<unsigned long long*>(mb + (gid >> 5)) = bal;
    } else if (blk < 33536) {                // ---- transW
        const int e = blk - 32768;
        const int mat = e >> 8, bx = e & 255;
        const int idx = bx * 256 + t;
        const int n = idx >> 8, k = idx & 255;
        const float* W = (mat == 0) ? WQ : (mat == 1) ? WK : WV;
        WT[(size_t)mat * 65536 + idx] = __float2bfloat16(W[(size_t)k * 256 + n]);
    } else if (blk < 34048) {                // ---- embtrans -> embT
        const int e = blk - 33536;
        const int lc = e & 15, b = e >> 4;
        const int l0 = lc * 32;
#pragma unroll 4
        for (int i = 0; i < 32; ++i)
            tile[i][t] = __float2bfloat16(emb[((size_t)b * 512 + l0 + i) * 256 + t]);
        __syncthreads();
        __hip_bfloat16* dst = embT + ((size_t)b * 256 + t) * 512 + l0;
#pragma unroll
        for (int i0 = 0; i0 < 32; i0 += 8) {
            bf16x8 v;
#pragma unroll
            for (int j = 0; j < 8; ++j) v[j] = *reinterpret_cast<short*>(&tile[i0 + j][t]);
            *reinterpret_cast<bf16x8*>(dst + i0) = v;
        }
    } else {                                 // ---- avg partials (2-stage preserved)
        const int bg = blk - 34048;
        const int b = bg >> 3, g = bg & 7;
        if (t < 64) mk[t] = imask[b * L + g * 64 + t];
        __syncthreads();
        float s = 0.f;
#pragma unroll 4
        for (int i = 0; i < 64; ++i)
            if (mk[i]) s += emb[((size_t)b * L + g * 64 + i) * 256 + t];
        avp[(size_t)bg * 256 + t] = s;
        if (t == 0) {
            int c = 0;
#pragma unroll
            for (int i = 0; i < 64; ++i) c += (mk[i] != 0);
            avc[bg] = (float)c;
        }
    }
}

__global__ __launch_bounds__(256) void avg_comb(const float* __restrict__ avp,
                                                const float* __restrict__ avc,
                                                __hip_bfloat16* __restrict__ xR) {
    const int b = blockIdx.x;
    const int t = threadIdx.x;
    float s = 0.f, c = 0.f;
#pragma unroll
    for (int g = 0; g < 8; ++g) {
        s += avp[(size_t)(b * 8 + g) * 256 + t];
        c += avc[b * 8 + g];
    }
    xR[(size_t)b * CONCAT + 65536 + t] = __float2bfloat16(s / fmaxf(c, 1.f));
}

// ---------------- QKV projection via MFMA (r15) ----------------
__global__ __launch_bounds__(256) void proj_mfma(const float* __restrict__ emb,
                                                 const __hip_bfloat16* __restrict__ WT,
                                                 __hip_bfloat16* __restrict__ Qb,
                                                 __hip_bfloat16* __restrict__ Kb,
                                                 __hip_bfloat16* __restrict__ Vt) {
    const int rb = blockIdx.x * 32;
    const int t = threadIdx.x;
    const int w = t >> 6, l = t & 63;
    const int lr = l & 15, lg = l >> 4;

    f32x4 accQ[2][4], accK[2][4], accV[2][4];
#pragma unroll
    for (int m = 0; m < 2; ++m)
#pragma unroll
        for (int n = 0; n < 4; ++n) {
            accQ[m][n] = (f32x4){0.f,0.f,0.f,0.f};
            accK[m][n] = (f32x4){0.f,0.f,0.f,0.f};
            accV[m][n] = (f32x4){0.f,0.f,0.f,0.f};
        }

    for (int kc = 0; kc < 8; ++kc) {
        const int k0 = kc * 32 + lg * 8;
        bf16x8 a[2];
#pragma unroll
        for (int m = 0; m < 2; ++m) {
            const float* ap = emb + (size_t)(rb + m * 16 + lr) * 256 + k0;
            float av[8];
#pragma unroll
            for (int j = 0; j < 8; ++j) av[j] = ap[j];
            a[m] = pack8(av);
        }
#pragma unroll
        for (int nt = 0; nt < 4; ++nt) {
            const int col = w * 64 + nt * 16 + lr;
            bf16x8 bq = *reinterpret_cast<const bf16x8*>(WT + (size_t)col * 256 + k0);
            bf16x8 bk = *reinterpret_cast<const bf16x8*>(WT + 65536 + (size_t)col * 256 + k0);
            bf16x8 bv = *reinterpret_cast<const bf16x8*>(WT + 131072 + (size_t)col * 256 + k0);
            accQ[0][nt] = __builtin_amdgcn_mfma_f32_16x16x32_bf16(a[0], bq, accQ[0][nt], 0, 0, 0);
            accQ[1][nt] = __builtin_amdgcn_mfma_f32_16x16x32_bf16(a[1], bq, accQ[1][nt], 0, 0, 0);
            accK[0][nt] = __builtin_amdgcn_mfma_f32_16x16x32_bf16(a[0], bk, accK[0][nt], 0, 0, 0);
            accK[1][nt] = __builtin_amdgcn_mfma_f32_16x16x32_bf16(a[1], bk, accK[1][nt], 0, 0, 0);
            accV[0][nt] = __builtin_amdgcn_mfma_f32_16x16x32_bf16(a[0], bv, accV[0][nt], 0, 0, 0);
            accV[1][nt] = __builtin_amdgcn_mfma_f32_16x16x32_bf16(a[1], bv, accV[1][nt], 0, 0, 0);
        }
    }

    const int b = rb >> 9, l0 = rb & 511;
#pragma unroll
    for (int m = 0; m < 2; ++m)
#pragma unroll
        for (int nt = 0; nt < 4; ++nt) {
            const int n = w * 64 + nt * 16 + lr;
            const int h = n >> 5, d = n & 31;
            const int bh = b * 8 + h;
#pragma unroll
            for (int r = 0; r < 4; ++r) {
                const int ll = l0 + m * 16 + lg * 4 + r;
                Qb[((size_t)bh * 512 + ll) * 32 + d] = __float2bfloat16(accQ[m][nt][r]);
                Kb[((size_t)bh * 512 + ll) * 32 + d] = __float2bfloat16(accK[m][nt][r]);
                Vt[((size_t)bh * 32 + d) * 512 + ll] = __float2bfloat16(accV[m][nt][r]);
            }
        }
}

// ---------------- MFMA attention v4 (r15 exact — 13.9 KB LDS, 8 blocks/CU) ----------------
__global__ __launch_bounds__(256) void attn_mfma(const __hip_bfloat16* __restrict__ Q,
                                                 const __hip_bfloat16* __restrict__ K,
                                                 const __hip_bfloat16* __restrict__ Vt,
                                                 const unsigned int* __restrict__ mb,
                                                 float* __restrict__ attn_out,
                                                 float* __restrict__ ctx) {
    const int qt = blockIdx.x;
    const int bh = blockIdx.y;
    const int b = bh >> 3, h = bh & 7;
    const int t = threadIdx.x;
    const int w = t >> 6, l = t & 63;
    const int lr = l & 15, lg = l >> 4;
    const int q0 = qt * 16;

    __shared__ __hip_bfloat16 Pl[4][16][40];
    __shared__ float rmax[4][16];
    __shared__ float rsum[4][16];
    __shared__ float Ored[4][16][32];

    const float scale = 0.17677669529663687f;

    const bf16x8 aq = *reinterpret_cast<const bf16x8*>(Q + ((size_t)bh * L + q0 + lr) * 32 + lg * 8);
    const __hip_bfloat16* Kbase = K + (size_t)bh * L * 32;

    f32x4 sc[8];
#pragma unroll
    for (int kt = 0; kt < 8; ++kt) {
        bf16x8 bk = *reinterpret_cast<const bf16x8*>(
            Kbase + (size_t)((w * 8 + kt) * 16 + lr) * 32 + lg * 8);
        sc[kt] = __builtin_amdgcn_mfma_f32_16x16x32_bf16(aq, bk, (f32x4){0.f,0.f,0.f,0.f}, 0, 0, 0);
    }

    float tmp[4];
#pragma unroll
    for (int r = 0; r < 4; ++r) {
        const int q = q0 + lg * 4 + r;
        uint4 mw = *reinterpret_cast<const uint4*>(mb + ((size_t)b * L + q) * 16 + w * 4);
        const unsigned int wds[4] = {mw.x, mw.y, mw.z, mw.w};
        float m = -3.4e38f;
#pragma unroll
        for (int kt = 0; kt < 8; ++kt) {
            unsigned bit = (unsigned)lr + ((kt & 1) << 4);
            float s = ((wds[kt >> 1] >> bit) & 1u) ? -1e9f : sc[kt][r] * scale;
            sc[kt][r] = s;
            m = fmaxf(m, s);
        }
        m = fmaxf(m, __shfl_xor(m, 1));
        m = fmaxf(m, __shfl_xor(m, 2));
        m = fmaxf(m, __shfl_xor(m, 4));
        m = fmaxf(m, __shfl_xor(m, 8));
        tmp[r] = m;
    }
    if (lr == 0) {
#pragma unroll
        for (int r = 0; r < 4; ++r) rmax[w][lg * 4 + r] = tmp[r];
    }
    __syncthreads();

#pragma unroll
    for (int r = 0; r < 4; ++r) {
        const int row = lg * 4 + r;
        const float gm = fmaxf(fmaxf(rmax[0][row], rmax[1][row]),
                               fmaxf(rmax[2][row], rmax[3][row]));
        float sum = 0.f;
#pragma unroll
        for (int kt = 0; kt < 8; ++kt) {
            float e = __expf(sc[kt][r] - gm);
            sc[kt][r] = e;
            sum += e;
        }
        sum += __shfl_xor(sum, 1);
        sum += __shfl_xor(sum, 2);
        sum += __shfl_xor(sum, 4);
        sum += __shfl_xor(sum, 8);
        tmp[r] = sum;
    }
    if (lr == 0) {
#pragma unroll
        for (int r = 0; r < 4; ++r) rsum[w][lg * 4 + r] = tmp[r];
    }
    __syncthreads();

    const float my_ri = 1.f / (rsum[0][lr] + rsum[1][lr] + rsum[2][lr] + rsum[3][lr]);

    f32x4 acc0 = {0.f,0.f,0.f,0.f}, acc1 = {0.f,0.f,0.f,0.f};
    const __hip_bfloat16* Vb = Vt + (size_t)bh * 32 * L;
    float* aob = attn_out + ((size_t)bh * L + q0 + lr) * L + w * 128;
#pragma unroll
    for (int cc = 0; cc < 4; ++cc) {
#pragma unroll
        for (int r = 0; r < 4; ++r) {
            Pl[w][lg * 4 + r][lr]      = __float2bfloat16(sc[2*cc  ][r]);
            Pl[w][lg * 4 + r][16 + lr] = __float2bfloat16(sc[2*cc+1][r]);
        }
        __syncthreads();
        bf16x8 ap = *reinterpret_cast<const bf16x8*>(&Pl[w][lr][lg * 8]);
        float4 o0, o1;
        o0.x = bf2f(ap[0]) * my_ri; o0.y = bf2f(ap[1]) * my_ri;
        o0.z = bf2f(ap[2]) * my_ri; o0.w = bf2f(ap[3]) * my_ri;
        o1.x = bf2f(ap[4]) * my_ri; o1.y = bf2f(ap[5]) * my_ri;
        o1.z = bf2f(ap[6]) * my_ri; o1.w = bf2f(ap[7]) * my_ri;
        float* ao = aob + cc * 32 + lg * 8;
        *reinterpret_cast<float4*>(ao)     = o0;
        *reinterpret_cast<float4*>(ao + 4) = o1;
        bf16x8 bv0 = *reinterpret_cast<const bf16x8*>(Vb + (size_t)lr        * L + w * 128 + cc * 32 + lg * 8);
        bf16x8 bv1 = *reinterpret_cast<const bf16x8*>(Vb + (size_t)(16 + lr) * L + w * 128 + cc * 32 + lg * 8);
        acc0 = __builtin_amdgcn_mfma_f32_16x16x32_bf16(ap, bv0, acc0, 0, 0, 0);
        acc1 = __builtin_amdgcn_mfma_f32_16x16x32_bf16(ap, bv1, acc1, 0, 0, 0);
        __syncthreads();
    }

#pragma unroll
    for (int r = 0; r < 4; ++r) {
        Ored[w][lg * 4 + r][lr]      = acc0[r];
        Ored[w][lg * 4 + r][16 + lr] = acc1[r];
    }
    __syncthreads();
    for (int v = t; v < 512; v += 256) {
        const int row = v >> 5, col = v & 31;
        const float s = Ored[0][row][col] + Ored[1][row][col]
                      + Ored[2][row][col] + Ored[3][row][col];
        const float gs = rsum[0][row] + rsum[1][row] + rsum[2][row] + rsum[3][row];
        ctx[((size_t)b * L + q0 + row) * 256 + h * 32 + col] = s / gs;
    }
}

// ---------------- column softmax v2 (r14) ----------------
__global__ __launch_bounds__(256) void wts_kernel(const float* __restrict__ ctx,
                                                  const int* __restrict__ imask,
                                                  __hip_bfloat16* __restrict__ wtsT) {
    const int b = blockIdx.x >> 3;
    const int ct = blockIdx.x & 7;
    const int t = threadIdx.x;
    const int c = ct * 32 + (t & 31);
    const int g = t >> 5;
    __shared__ float rm[8][32];
    __shared__ float rs[8][32];
    __shared__ int mk[512];
    for (int p = t; p < 512; p += 256) mk[p] = imask[b * 512 + p];
    __syncthreads();

    float m = -3.4e38f;
    for (int ll = g; ll < 512; ll += 8) {
        float v = mk[ll] ? ctx[((size_t)b * 512 + ll) * 256 + c] : -1e9f;
        m = fmaxf(m, v);
    }
    rm[g][t & 31] = m;
    __syncthreads();
    float M = rm[0][t & 31];
#pragma unroll
    for (int q = 1; q < 8; ++q) M = fmaxf(M, rm[q][t & 31]);

    float sum = 0.f;
    for (int ll = g; ll < 512; ll += 8) {
        float v = mk[ll] ? ctx[((size_t)b * 512 + ll) * 256 + c] : -1e9f;
        sum += __expf(v - M);
    }
    rs[g][t & 31] = sum;
    __syncthreads();
    float S = 0.f;
#pragma unroll
    for (int q = 0; q < 8; ++q) S += rs[q][t & 31];
    const float rinv = 1.f / S;

    __hip_bfloat16* wrow = wtsT + ((size_t)b * 256 + c) * 512;
    for (int ll = g; ll < 512; ll += 8) {
        float v = mk[ll] ? ctx[((size_t)b * 512 + ll) * 256 + c] : -1e9f;
        wrow[ll] = __float2bfloat16(__expf(v - M) * rinv);
    }
}

// ---------------- pooled via MFMA (unchanged) ----------------
__global__ __launch_bounds__(256) void pooled_mfma(const __hip_bfloat16* __restrict__ embT,
                                                   const __hip_bfloat16* __restrict__ wtsT,
                                                   __hip_bfloat16* __restrict__ xR) {
    const int ct = blockIdx.x, dt = blockIdx.y, b = blockIdx.z;
    const int t = threadIdx.x;
    const int w = t >> 6, l = t & 63;
    const int lr = l & 15, lg = l >> 4;
    const int wr = w >> 1, wc = w & 1;
    const int d0 = dt * 64 + wr * 32;
    const int c0 = ct * 64 + wc * 32;

    f32x4 acc[2][2];
#pragma unroll
    for (int m = 0; m < 2; ++m)
#pragma unroll
        for (int n = 0; n < 2; ++n) acc[m][n] = (f32x4){0.f,0.f,0.f,0.f};

    for (int lc = 0; lc < 16; ++lc) {
        const int lbase = lc * 32 + lg * 8;
        bf16x8 a[2], bb[2];
#pragma unroll
        for (int m = 0; m < 2; ++m)
            a[m] = *reinterpret_cast<const bf16x8*>(
                embT + ((size_t)b * 256 + d0 + m * 16 + lr) * 512 + lbase);
#pragma unroll
        for (int n = 0; n < 2; ++n)
            bb[n] = *reinterpret_cast<const bf16x8*>(
                wtsT + ((size_t)b * 256 + c0 + n * 16 + lr) * 512 + lbase);
#pragma unroll
        for (int m = 0; m < 2; ++m)
#pragma unroll
            for (int n = 0; n < 2; ++n)
                acc[m][n] = __builtin_amdgcn_mfma_f32_16x16x32_bf16(a[m], bb[n], acc[m][n], 0, 0, 0);
    }
#pragma unroll
    for (int m = 0; m < 2; ++m)
#pragma unroll
        for (int n = 0; n < 2; ++n)
#pragma unroll
            for (int r = 0; r < 4; ++r) {
                const int d = d0 + m * 16 + lg * 4 + r;
                const int c = c0 + n * 16 + lr;
                xR[(size_t)b * CONCAT + d * 256 + c] = __float2bfloat16(acc[m][n][r]);
            }
}

// ---------------- fc via MFMA; unroll 4 (the ONE change vs r15) ----------------
template<int KSTEPS, int XSTRIDE, int CHUNK>
__global__ __launch_bounds__(256) void fc_mfma(const __hip_bfloat16* __restrict__ xR,
                                               const float* __restrict__ Wf,
                                               float* __restrict__ part,
                                               int kcbase) {
    const int bx = blockIdx.x;
    const int kc = blockIdx.y + kcbase;
    const int kbase = kc * CHUNK;
    const int t = threadIdx.x;
    const int w = t >> 6, l = t & 63;
    const int lr = l & 15, lg = l >> 4;
    const int col0 = bx * 256 + w * 64;

    f32x4 acc[2][4];
#pragma unroll
    for (int m = 0; m < 2; ++m)
#pragma unroll
        for (int n = 0; n < 4; ++n) acc[m][n] = (f32x4){0.f,0.f,0.f,0.f};

#pragma unroll 4
    for (int kt = 0; kt < KSTEPS; ++kt) {
        const int k = kbase + kt * 32 + lg * 8;
        bf16x8 a0 = *reinterpret_cast<const bf16x8*>(xR + (size_t)lr * XSTRIDE + k);
        bf16x8 a1 = *reinterpret_cast<const bf16x8*>(xR + (size_t)(16 + lr) * XSTRIDE + k);
#pragma unroll
        for (int nt = 0; nt < 4; ++nt) {
            const float* wp = Wf + (size_t)k * 2048 + col0 + nt * 16 + lr;
            float wv[8];
#pragma unroll
            for (int j = 0; j < 8; ++j) wv[j] = wp[(size_t)j * 2048];
            bf16x8 bw = pack8(wv);
            acc[0][nt] = __builtin_amdgcn_mfma_f32_16x16x32_bf16(a0, bw, acc[0][nt], 0, 0, 0);
            acc[1][nt] = __builtin_amdgcn_mfma_f32_16x16x32_bf16(a1, bw, acc[1][nt], 0, 0, 0);
        }
    }
    float* pp = part + (size_t)kc * 65536;
#pragma unroll
    for (int m = 0; m < 2; ++m)
#pragma unroll
        for (int nt = 0; nt < 4; ++nt)
#pragma unroll
            for (int r = 0; r < 4; ++r) {
                const int bb = m * 16 + lg * 4 + r;
                pp[(size_t)bb * 2048 + col0 + nt * 16 + lr] = acc[m][nt][r];
            }
}

// ---------------- fc1 reduce (r14) ----------------
__global__ __launch_bounds__(256) void fcreduce1(const float* __restrict__ part,
                                                 const float* __restrict__ bias,
                                                 __hip_bfloat16* __restrict__ outR) {
    const int t = threadIdx.x;
    const int o = blockIdx.x * 128 + (t & 127);
    const int half = t >> 7;
    __shared__ float red[128];
    float s = 0.f;
    if (half == 0) {
        for (int kc = 0; kc < 65; ++kc) s += part[(size_t)kc * 65536 + o];
    } else {
        for (int kc = 65; kc < 129; ++kc) s += part[(size_t)kc * 65536 + o];
    }
    if (half) red[t & 127] = s;
    __syncthreads();
    if (!half) {
        s += red[t];
        const int col = o & 2047;
        s = fmaxf(s + bias[col], 0.f);
        outR[o] = __float2bfloat16(s);
    }
}

// ---------------- fc23 (r14) ----------------
__global__ __launch_bounds__(256) void fc23_kernel(const float* __restrict__ part2,
                                                   const float* __restrict__ b2,
                                                   const float* __restrict__ w3,
                                                   const float* __restrict__ b3,
                                                   float* __restrict__ out) {
    const int b = blockIdx.x;
    const int t = threadIdx.x;
    float s = 0.f;
    for (int c = t; c < DFF; c += 256) {
        float v = 0.f;
#pragma unroll
        for (int kc = 0; kc < 16; ++kc) v += part2[(size_t)kc * 65536 + b * 2048 + c];
        v = fmaxf(v + b2[c], 0.f);
        s += v * w3[c];
    }
#pragma unroll
    for (int o = 1; o < 64; o <<= 1) s += __shfl_xor(s, o);
    __shared__ float red[4];
    if ((t & 63) == 0) red[t >> 6] = s;
    __syncthreads();
    if (t == 0) out[b] = red[0] + red[1] + red[2] + red[3] + b3[0];
}

extern "C" void kernel_launch(void* const* d_in, const int* in_sizes, int n_in,
                              void* d_out, int out_size, void* d_ws, size_t ws_size,
                              hipStream_t stream) {
    const float* emb   = (const float*)d_in[0];
    const int*   amask = (const int*)d_in[1];
    const int*   imask = (const int*)d_in[2];
    const float* WQ    = (const float*)d_in[3];
    const float* WK    = (const float*)d_in[4];
    const float* WV    = (const float*)d_in[5];
    const float* fc1w  = (const float*)d_in[6];
    const float* fc1b  = (const float*)d_in[7];
    const float* fc2w  = (const float*)d_in[8];
    const float* fc2b  = (const float*)d_in[9];
    const float* fc3w  = (const float*)d_in[10];
    const float* fc3b  = (const float*)d_in[11];

    float* out_head = (float*)d_out;
    float* attn_out = out_head + 32;

    float* ws = (float*)d_ws;
    const size_t OFF_XR   = 0;
    const size_t OFF_Q    = OFF_XR + 1052672;
    const size_t OFF_K    = OFF_Q + 2097152;
    const size_t OFF_V    = OFF_K + 2097152;
    const size_t OFF_CTX  = OFF_V + 2097152;
    const size_t OFF_WTST = OFF_CTX + 4194304;
    const size_t OFF_P1   = OFF_WTST + 2097152;
    const size_t OFF_H1   = OFF_P1 + 8454144;
    const size_t OFF_P2   = OFF_H1 + 32768;
    const size_t OFF_MB   = OFF_P2 + 1048576;
    const size_t OFF_AVP  = OFF_MB + 262144;
    const size_t OFF_EMBT = OFF_AVP + 65792;
    const size_t OFF_WT   = OFF_EMBT + 2097152;

    __hip_bfloat16* xR   = (__hip_bfloat16*)(ws + OFF_XR);
    __hip_bfloat16* Qb   = (__hip_bfloat16*)(ws + OFF_Q);
    __hip_bfloat16* Kb   = (__hip_bfloat16*)(ws + OFF_K);
    __hip_bfloat16* Vt   = (__hip_bfloat16*)(ws + OFF_V);
    float* ctx   = ws + OFF_CTX;
    __hip_bfloat16* wtsT = (__hip_bfloat16*)(ws + OFF_WTST);
    float* part1 = ws + OFF_P1;
    __hip_bfloat16* h1R  = (__hip_bfloat16*)(ws + OFF_H1);
    float* part2 = ws + OFF_P2;
    unsigned int* mbits = (unsigned int*)(ws + OFF_MB);
    float* avp   = ws + OFF_AVP;
    float* avc   = ws + OFF_AVP + 65536;
    __hip_bfloat16* embT = (__hip_bfloat16*)(ws + OFF_EMBT);
    __hip_bfloat16* WT   = (__hip_bfloat16*)(ws + OFF_WT);

    prep_kernel<<<dim3(34304), 256, 0, stream>>>(amask, mbits, WQ, WK, WV, WT,
                                                 emb, embT, imask, avp, avc);
    proj_mfma<<<dim3(512), 256, 0, stream>>>(emb, WT, Qb, Kb, Vt);
    attn_mfma<<<dim3(32, BH), 256, 0, stream>>>(Qb, Kb, Vt, mbits, attn_out, ctx);
    wts_kernel<<<dim3(B * 8), 256, 0, stream>>>(ctx, imask, wtsT);
    pooled_mfma<<<dim3(4, 4, B), 256, 0, stream>>>(embT, wtsT, xR);
    avg_comb<<<dim3(B), 256, 0, stream>>>(avp, avc, xR);

    fc_mfma<16, CONCAT, 512><<<dim3(8, 128), 256, 0, stream>>>(xR, fc1w, part1, 0);
    fc_mfma<8, CONCAT, 512><<<dim3(8, 1), 256, 0, stream>>>(xR, fc1w, part1, 128);
    fcreduce1<<<dim3(512), 256, 0, stream>>>(part1, fc1b, h1R);

    fc_mfma<4, DFF, 128><<<dim3(8, 16), 256, 0, stream>>>(h1R, fc2w, part2, 0);
    fc23_kernel<<<dim3(B), 256, 0, stream>>>(part2, fc2b, fc3w, fc3b, out_head);
}

// Round 18
// 411.055 us; speedup vs baseline: 1.0409x; 1.0291x over previous
//
#include <hip/hip_runtime.h>
#include <hip/hip_bf16.h>
#include <cstdint>

namespace {
constexpr int B  = 32;
constexpr int L  = 512;
constexpr int D  = 256;
constexpr int H  = 8;
constexpr int DV = 32;
constexpr int DFF = 2048;
constexpr int CONCAT = D * H * DV + D;   // 65792
constexpr int BH = B * H;                // 256
}

typedef __attribute__((ext_vector_type(8))) short bf16x8;
typedef __attribute__((ext_vector_type(4))) float f32x4;

static __device__ __forceinline__ unsigned short f2bf_bits(float x) {
    __hip_bfloat16 h = __float2bfloat16(x);
    return *reinterpret_cast<unsigned short*>(&h);
}
static __device__ __forceinline__ float bf2f(short u) {
    unsigned int x = ((unsigned int)(unsigned short)u) << 16;
    union { unsigned int u; float f; } c; c.u = x; return c.f;
}
static __device__ __forceinline__ bf16x8 pack8(const float* v) {
    bf16x8 r;
#pragma unroll
    for (int j = 0; j < 8; ++j) r[j] = (short)f2bf_bits(v[j]);
    return r;
}

// ---------------- fused prep v2: maskpack | transW | embtrans(T only) | avg_part ----------------
__global__ __launch_bounds__(256) void prep_kernel(const int* __restrict__ amask,
                                                   unsigned int* __restrict__ mb,
                                                   const float* __restrict__ WQ,
                                                   const float* __restrict__ WK,
                                                   const float* __restrict__ WV,
                                                   __hip_bfloat16* __restrict__ WT,
                                                   const float* __restrict__ emb,
                                                   __hip_bfloat16* __restrict__ embT,
                                                   const int* __restrict__ imask,
                                                   float* __restrict__ avp,
                                                   float* __restrict__ avc) {
    __shared__ __hip_bfloat16 tile[32][264];
    __shared__ int mk[64];
    const int blk = blockIdx.x;
    const int t = threadIdx.x;

    if (blk < 32768) {                       // ---- maskpack
        const size_t gid = (size_t)blk * 256 + t;
        int v = amask[gid];
        unsigned long long bal = __ballot(v != 0);
        if ((t & 63) == 0) *reinterpret_cast<unsigned long long*>(mb + (gid >> 5)) = bal;
    } else if (blk < 33536) {                // ---- transW
        const int e = blk - 32768;
        const int mat = e >> 8, bx = e & 255;
        const int idx = bx * 256 + t;
        const int n = idx >> 8, k = idx & 255;
        const float* W = (mat == 0) ? WQ : (mat == 1) ? WK : WV;
        WT[(size_t)mat * 65536 + idx] = __float2bfloat16(W[(size_t)k * 256 + n]);
    } else if (blk < 34048) {                // ---- embtrans -> embT
        const int e = blk - 33536;
        const int lc = e & 15, b = e >> 4;
        const int l0 = lc * 32;
#pragma unroll 4
        for (int i = 0; i < 32; ++i)
            tile[i][t] = __float2bfloat16(emb[((size_t)b * 512 + l0 + i) * 256 + t]);
        __syncthreads();
        __hip_bfloat16* dst = embT + ((size_t)b * 256 + t) * 512 + l0;
#pragma unroll
        for (int i0 = 0; i0 < 32; i0 += 8) {
            bf16x8 v;
#pragma unroll
            for (int j = 0; j < 8; ++j) v[j] = *reinterpret_cast<short*>(&tile[i0 + j][t]);
            *reinterpret_cast<bf16x8*>(dst + i0) = v;
        }
    } else {                                 // ---- avg partials (2-stage preserved)
        const int bg = blk - 34048;
        const int b = bg >> 3, g = bg & 7;
        if (t < 64) mk[t] = imask[b * L + g * 64 + t];
        __syncthreads();
        float s = 0.f;
#pragma unroll 4
        for (int i = 0; i < 64; ++i)
            if (mk[i]) s += emb[((size_t)b * L + g * 64 + i) * 256 + t];
        avp[(size_t)bg * 256 + t] = s;
        if (t == 0) {
            int c = 0;
#pragma unroll
            for (int i = 0; i < 64; ++i) c += (mk[i] != 0);
            avc[bg] = (float)c;
        }
    }
}

__global__ __launch_bounds__(256) void avg_comb(const float* __restrict__ avp,
                                                const float* __restrict__ avc,
                                                __hip_bfloat16* __restrict__ xR) {
    const int b = blockIdx.x;
    const int t = threadIdx.x;
    float s = 0.f, c = 0.f;
#pragma unroll
    for (int g = 0; g < 8; ++g) {
        s += avp[(size_t)(b * 8 + g) * 256 + t];
        c += avc[b * 8 + g];
    }
    xR[(size_t)b * CONCAT + 65536 + t] = __float2bfloat16(s / fmaxf(c, 1.f));
}

// ---------------- QKV projection via MFMA ----------------
__global__ __launch_bounds__(256) void proj_mfma(const float* __restrict__ emb,
                                                 const __hip_bfloat16* __restrict__ WT,
                                                 __hip_bfloat16* __restrict__ Qb,
                                                 __hip_bfloat16* __restrict__ Kb,
                                                 __hip_bfloat16* __restrict__ Vt) {
    const int rb = blockIdx.x * 32;
    const int t = threadIdx.x;
    const int w = t >> 6, l = t & 63;
    const int lr = l & 15, lg = l >> 4;

    f32x4 accQ[2][4], accK[2][4], accV[2][4];
#pragma unroll
    for (int m = 0; m < 2; ++m)
#pragma unroll
        for (int n = 0; n < 4; ++n) {
            accQ[m][n] = (f32x4){0.f,0.f,0.f,0.f};
            accK[m][n] = (f32x4){0.f,0.f,0.f,0.f};
            accV[m][n] = (f32x4){0.f,0.f,0.f,0.f};
        }

    for (int kc = 0; kc < 8; ++kc) {
        const int k0 = kc * 32 + lg * 8;
        bf16x8 a[2];
#pragma unroll
        for (int m = 0; m < 2; ++m) {
            const float* ap = emb + (size_t)(rb + m * 16 + lr) * 256 + k0;
            float av[8];
#pragma unroll
            for (int j = 0; j < 8; ++j) av[j] = ap[j];
            a[m] = pack8(av);
        }
#pragma unroll
        for (int nt = 0; nt < 4; ++nt) {
            const int col = w * 64 + nt * 16 + lr;
            bf16x8 bq = *reinterpret_cast<const bf16x8*>(WT + (size_t)col * 256 + k0);
            bf16x8 bk = *reinterpret_cast<const bf16x8*>(WT + 65536 + (size_t)col * 256 + k0);
            bf16x8 bv = *reinterpret_cast<const bf16x8*>(WT + 131072 + (size_t)col * 256 + k0);
            accQ[0][nt] = __builtin_amdgcn_mfma_f32_16x16x32_bf16(a[0], bq, accQ[0][nt], 0, 0, 0);
            accQ[1][nt] = __builtin_amdgcn_mfma_f32_16x16x32_bf16(a[1], bq, accQ[1][nt], 0, 0, 0);
            accK[0][nt] = __builtin_amdgcn_mfma_f32_16x16x32_bf16(a[0], bk, accK[0][nt], 0, 0, 0);
            accK[1][nt] = __builtin_amdgcn_mfma_f32_16x16x32_bf16(a[1], bk, accK[1][nt], 0, 0, 0);
            accV[0][nt] = __builtin_amdgcn_mfma_f32_16x16x32_bf16(a[0], bv, accV[0][nt], 0, 0, 0);
            accV[1][nt] = __builtin_amdgcn_mfma_f32_16x16x32_bf16(a[1], bv, accV[1][nt], 0, 0, 0);
        }
    }

    const int b = rb >> 9, l0 = rb & 511;
#pragma unroll
    for (int m = 0; m < 2; ++m)
#pragma unroll
        for (int nt = 0; nt < 4; ++nt) {
            const int n = w * 64 + nt * 16 + lr;
            const int h = n >> 5, d = n & 31;
            const int bh = b * 8 + h;
#pragma unroll
            for (int r = 0; r < 4; ++r) {
                const int ll = l0 + m * 16 + lg * 4 + r;
                Qb[((size_t)bh * 512 + ll) * 32 + d] = __float2bfloat16(accQ[m][nt][r]);
                Kb[((size_t)bh * 512 + ll) * 32 + d] = __float2bfloat16(accK[m][nt][r]);
                Vt[((size_t)bh * 32 + d) * 512 + ll] = __float2bfloat16(accV[m][nt][r]);
            }
        }
}

// ---------------- MFMA attention v4 (r15) ----------------
__global__ __launch_bounds__(256) void attn_mfma(const __hip_bfloat16* __restrict__ Q,
                                                 const __hip_bfloat16* __restrict__ K,
                                                 const __hip_bfloat16* __restrict__ Vt,
                                                 const unsigned int* __restrict__ mb,
                                                 float* __restrict__ attn_out,
                                                 float* __restrict__ ctx) {
    const int qt = blockIdx.x;
    const int bh = blockIdx.y;
    const int b = bh >> 3, h = bh & 7;
    const int t = threadIdx.x;
    const int w = t >> 6, l = t & 63;
    const int lr = l & 15, lg = l >> 4;
    const int q0 = qt * 16;

    __shared__ __hip_bfloat16 Pl[4][16][40];
    __shared__ float rmax[4][16];
    __shared__ float rsum[4][16];
    __shared__ float Ored[4][16][32];

    const float scale = 0.17677669529663687f;

    const bf16x8 aq = *reinterpret_cast<const bf16x8*>(Q + ((size_t)bh * L + q0 + lr) * 32 + lg * 8);
    const __hip_bfloat16* Kbase = K + (size_t)bh * L * 32;

    f32x4 sc[8];
#pragma unroll
    for (int kt = 0; kt < 8; ++kt) {
        bf16x8 bk = *reinterpret_cast<const bf16x8*>(
            Kbase + (size_t)((w * 8 + kt) * 16 + lr) * 32 + lg * 8);
        sc[kt] = __builtin_amdgcn_mfma_f32_16x16x32_bf16(aq, bk, (f32x4){0.f,0.f,0.f,0.f}, 0, 0, 0);
    }

    float tmp[4];
#pragma unroll
    for (int r = 0; r < 4; ++r) {
        const int q = q0 + lg * 4 + r;
        uint4 mw = *reinterpret_cast<const uint4*>(mb + ((size_t)b * L + q) * 16 + w * 4);
        const unsigned int wds[4] = {mw.x, mw.y, mw.z, mw.w};
        float m = -3.4e38f;
#pragma unroll
        for (int kt = 0; kt < 8; ++kt) {
            unsigned bit = (unsigned)lr + ((kt & 1) << 4);
            float s = ((wds[kt >> 1] >> bit) & 1u) ? -1e9f : sc[kt][r] * scale;
            sc[kt][r] = s;
            m = fmaxf(m, s);
        }
        m = fmaxf(m, __shfl_xor(m, 1));
        m = fmaxf(m, __shfl_xor(m, 2));
        m = fmaxf(m, __shfl_xor(m, 4));
        m = fmaxf(m, __shfl_xor(m, 8));
        tmp[r] = m;
    }
    if (lr == 0) {
#pragma unroll
        for (int r = 0; r < 4; ++r) rmax[w][lg * 4 + r] = tmp[r];
    }
    __syncthreads();

#pragma unroll
    for (int r = 0; r < 4; ++r) {
        const int row = lg * 4 + r;
        const float gm = fmaxf(fmaxf(rmax[0][row], rmax[1][row]),
                               fmaxf(rmax[2][row], rmax[3][row]));
        float sum = 0.f;
#pragma unroll
        for (int kt = 0; kt < 8; ++kt) {
            float e = __expf(sc[kt][r] - gm);
            sc[kt][r] = e;
            sum += e;
        }
        sum += __shfl_xor(sum, 1);
        sum += __shfl_xor(sum, 2);
        sum += __shfl_xor(sum, 4);
        sum += __shfl_xor(sum, 8);
        tmp[r] = sum;
    }
    if (lr == 0) {
#pragma unroll
        for (int r = 0; r < 4; ++r) rsum[w][lg * 4 + r] = tmp[r];
    }
    __syncthreads();

    const float my_ri = 1.f / (rsum[0][lr] + rsum[1][lr] + rsum[2][lr] + rsum[3][lr]);

    f32x4 acc0 = {0.f,0.f,0.f,0.f}, acc1 = {0.f,0.f,0.f,0.f};
    const __hip_bfloat16* Vb = Vt + (size_t)bh * 32 * L;
    float* aob = attn_out + ((size_t)bh * L + q0 + lr) * L + w * 128;
#pragma unroll
    for (int cc = 0; cc < 4; ++cc) {
#pragma unroll
        for (int r = 0; r < 4; ++r) {
            Pl[w][lg * 4 + r][lr]      = __float2bfloat16(sc[2*cc  ][r]);
            Pl[w][lg * 4 + r][16 + lr] = __float2bfloat16(sc[2*cc+1][r]);
        }
        __syncthreads();
        bf16x8 ap = *reinterpret_cast<const bf16x8*>(&Pl[w][lr][lg * 8]);
        float4 o0, o1;
        o0.x = bf2f(ap[0]) * my_ri; o0.y = bf2f(ap[1]) * my_ri;
        o0.z = bf2f(ap[2]) * my_ri; o0.w = bf2f(ap[3]) * my_ri;
        o1.x = bf2f(ap[4]) * my_ri; o1.y = bf2f(ap[5]) * my_ri;
        o1.z = bf2f(ap[6]) * my_ri; o1.w = bf2f(ap[7]) * my_ri;
        float* ao = aob + cc * 32 + lg * 8;
        *reinterpret_cast<float4*>(ao)     = o0;
        *reinterpret_cast<float4*>(ao + 4) = o1;
        bf16x8 bv0 = *reinterpret_cast<const bf16x8*>(Vb + (size_t)lr        * L + w * 128 + cc * 32 + lg * 8);
        bf16x8 bv1 = *reinterpret_cast<const bf16x8*>(Vb + (size_t)(16 + lr) * L + w * 128 + cc * 32 + lg * 8);
        acc0 = __builtin_amdgcn_mfma_f32_16x16x32_bf16(ap, bv0, acc0, 0, 0, 0);
        acc1 = __builtin_amdgcn_mfma_f32_16x16x32_bf16(ap, bv1, acc1, 0, 0, 0);
        __syncthreads();
    }

#pragma unroll
    for (int r = 0; r < 4; ++r) {
        Ored[w][lg * 4 + r][lr]      = acc0[r];
        Ored[w][lg * 4 + r][16 + lr] = acc1[r];
    }
    __syncthreads();
    for (int v = t; v < 512; v += 256) {
        const int row = v >> 5, col = v & 31;
        const float s = Ored[0][row][col] + Ored[1][row][col]
                      + Ored[2][row][col] + Ored[3][row][col];
        const float gs = rsum[0][row] + rsum[1][row] + rsum[2][row] + rsum[3][row];
        ctx[((size_t)b * L + q0 + row) * 256 + h * 32 + col] = s / gs;
    }
}

// ---------------- column softmax v2 (r14) ----------------
__global__ __launch_bounds__(256) void wts_kernel(const float* __restrict__ ctx,
                                                  const int* __restrict__ imask,
                                                  __hip_bfloat16* __restrict__ wtsT) {
    const int b = blockIdx.x >> 3;
    const int ct = blockIdx.x & 7;
    const int t = threadIdx.x;
    const int c = ct * 32 + (t & 31);
    const int g = t >> 5;
    __shared__ float rm[8][32];
    __shared__ float rs[8][32];
    __shared__ int mk[512];
    for (int p = t; p < 512; p += 256) mk[p] = imask[b * 512 + p];
    __syncthreads();

    float m = -3.4e38f;
    for (int ll = g; ll < 512; ll += 8) {
        float v = mk[ll] ? ctx[((size_t)b * 512 + ll) * 256 + c] : -1e9f;
        m = fmaxf(m, v);
    }
    rm[g][t & 31] = m;
    __syncthreads();
    float M = rm[0][t & 31];
#pragma unroll
    for (int q = 1; q < 8; ++q) M = fmaxf(M, rm[q][t & 31]);

    float sum = 0.f;
    for (int ll = g; ll < 512; ll += 8) {
        float v = mk[ll] ? ctx[((size_t)b * 512 + ll) * 256 + c] : -1e9f;
        sum += __expf(v - M);
    }
    rs[g][t & 31] = sum;
    __syncthreads();
    float S = 0.f;
#pragma unroll
    for (int q = 0; q < 8; ++q) S += rs[q][t & 31];
    const float rinv = 1.f / S;

    __hip_bfloat16* wrow = wtsT + ((size_t)b * 256 + c) * 512;
    for (int ll = g; ll < 512; ll += 8) {
        float v = mk[ll] ? ctx[((size_t)b * 512 + ll) * 256 + c] : -1e9f;
        wrow[ll] = __float2bfloat16(__expf(v - M) * rinv);
    }
}

// ---------------- pooled via MFMA ----------------
__global__ __launch_bounds__(256) void pooled_mfma(const __hip_bfloat16* __restrict__ embT,
                                                   const __hip_bfloat16* __restrict__ wtsT,
                                                   __hip_bfloat16* __restrict__ xR) {
    const int ct = blockIdx.x, dt = blockIdx.y, b = blockIdx.z;
    const int t = threadIdx.x;
    const int w = t >> 6, l = t & 63;
    const int lr = l & 15, lg = l >> 4;
    const int wr = w >> 1, wc = w & 1;
    const int d0 = dt * 64 + wr * 32;
    const int c0 = ct * 64 + wc * 32;

    f32x4 acc[2][2];
#pragma unroll
    for (int m = 0; m < 2; ++m)
#pragma unroll
        for (int n = 0; n < 2; ++n) acc[m][n] = (f32x4){0.f,0.f,0.f,0.f};

    for (int lc = 0; lc < 16; ++lc) {
        const int lbase = lc * 32 + lg * 8;
        bf16x8 a[2], bb[2];
#pragma unroll
        for (int m = 0; m < 2; ++m)
            a[m] = *reinterpret_cast<const bf16x8*>(
                embT + ((size_t)b * 256 + d0 + m * 16 + lr) * 512 + lbase);
#pragma unroll
        for (int n = 0; n < 2; ++n)
            bb[n] = *reinterpret_cast<const bf16x8*>(
                wtsT + ((size_t)b * 256 + c0 + n * 16 + lr) * 512 + lbase);
#pragma unroll
        for (int m = 0; m < 2; ++m)
#pragma unroll
            for (int n = 0; n < 2; ++n)
                acc[m][n] = __builtin_amdgcn_mfma_f32_16x16x32_bf16(a[m], bb[n], acc[m][n], 0, 0, 0);
    }
#pragma unroll
    for (int m = 0; m < 2; ++m)
#pragma unroll
        for (int n = 0; n < 2; ++n)
#pragma unroll
            for (int r = 0; r < 4; ++r) {
                const int d = d0 + m * 16 + lg * 4 + r;
                const int c = c0 + n * 16 + lr;
                xR[(size_t)b * CONCAT + d * 256 + c] = __float2bfloat16(acc[m][n][r]);
            }
}

// ---------------- fc via MFMA; CHUNK = K per kc slot; unroll 2 ----------------
template<int KSTEPS, int XSTRIDE, int CHUNK>
__global__ __launch_bounds__(256) void fc_mfma(const __hip_bfloat16* __restrict__ xR,
                                               const float* __restrict__ Wf,
                                               float* __restrict__ part,
                                               int kcbase) {
    const int bx = blockIdx.x;
    const int kc = blockIdx.y + kcbase;
    const int kbase = kc * CHUNK;
    const int t = threadIdx.x;
    const int w = t >> 6, l = t & 63;
    const int lr = l & 15, lg = l >> 4;
    const int col0 = bx * 256 + w * 64;

    f32x4 acc[2][4];
#pragma unroll
    for (int m = 0; m < 2; ++m)
#pragma unroll
        for (int n = 0; n < 4; ++n) acc[m][n] = (f32x4){0.f,0.f,0.f,0.f};

#pragma unroll 2
    for (int kt = 0; kt < KSTEPS; ++kt) {
        const int k = kbase + kt * 32 + lg * 8;
        bf16x8 a0 = *reinterpret_cast<const bf16x8*>(xR + (size_t)lr * XSTRIDE + k);
        bf16x8 a1 = *reinterpret_cast<const bf16x8*>(xR + (size_t)(16 + lr) * XSTRIDE + k);
#pragma unroll
        for (int nt = 0; nt < 4; ++nt) {
            const float* wp = Wf + (size_t)k * 2048 + col0 + nt * 16 + lr;
            float wv[8];
#pragma unroll
            for (int j = 0; j < 8; ++j) wv[j] = wp[(size_t)j * 2048];
            bf16x8 bw = pack8(wv);
            acc[0][nt] = __builtin_amdgcn_mfma_f32_16x16x32_bf16(a0, bw, acc[0][nt], 0, 0, 0);
            acc[1][nt] = __builtin_amdgcn_mfma_f32_16x16x32_bf16(a1, bw, acc[1][nt], 0, 0, 0);
        }
    }
    float* pp = part + (size_t)kc * 65536;
#pragma unroll
    for (int m = 0; m < 2; ++m)
#pragma unroll
        for (int nt = 0; nt < 4; ++nt)
#pragma unroll
            for (int r = 0; r < 4; ++r) {
                const int bb = m * 16 + lg * 4 + r;
                pp[(size_t)bb * 2048 + col0 + nt * 16 + lr] = acc[m][nt][r];
            }
}

// ---------------- fc1 reduce (r14) ----------------
__global__ __launch_bounds__(256) void fcreduce1(const float* __restrict__ part,
                                                 const float* __restrict__ bias,
                                                 __hip_bfloat16* __restrict__ outR) {
    const int t = threadIdx.x;
    const int o = blockIdx.x * 128 + (t & 127);
    const int half = t >> 7;
    __shared__ float red[128];
    float s = 0.f;
    if (half == 0) {
        for (int kc = 0; kc < 65; ++kc) s += part[(size_t)kc * 65536 + o];
    } else {
        for (int kc = 65; kc < 129; ++kc) s += part[(size_t)kc * 65536 + o];
    }
    if (half) red[t & 127] = s;
    __syncthreads();
    if (!half) {
        s += red[t];
        const int col = o & 2047;
        s = fmaxf(s + bias[col], 0.f);
        outR[o] = __float2bfloat16(s);
    }
}

// ---------------- fc23 (r14) ----------------
__global__ __launch_bounds__(256) void fc23_kernel(const float* __restrict__ part2,
                                                   const float* __restrict__ b2,
                                                   const float* __restrict__ w3,
                                                   const float* __restrict__ b3,
                                                   float* __restrict__ out) {
    const int b = blockIdx.x;
    const int t = threadIdx.x;
    float s = 0.f;
    for (int c = t; c < DFF; c += 256) {
        float v = 0.f;
#pragma unroll
        for (int kc = 0; kc < 16; ++kc) v += part2[(size_t)kc * 65536 + b * 2048 + c];
        v = fmaxf(v + b2[c], 0.f);
        s += v * w3[c];
    }
#pragma unroll
    for (int o = 1; o < 64; o <<= 1) s += __shfl_xor(s, o);
    __shared__ float red[4];
    if ((t & 63) == 0) red[t >> 6] = s;
    __syncthreads();
    if (t == 0) out[b] = red[0] + red[1] + red[2] + red[3] + b3[0];
}

extern "C" void kernel_launch(void* const* d_in, const int* in_sizes, int n_in,
                              void* d_out, int out_size, void* d_ws, size_t ws_size,
                              hipStream_t stream) {
    const float* emb   = (const float*)d_in[0];
    const int*   amask = (const int*)d_in[1];
    const int*   imask = (const int*)d_in[2];
    const float* WQ    = (const float*)d_in[3];
    const float* WK    = (const float*)d_in[4];
    const float* WV    = (const float*)d_in[5];
    const float* fc1w  = (const float*)d_in[6];
    const float* fc1b  = (const float*)d_in[7];
    const float* fc2w  = (const float*)d_in[8];
    const float* fc2b  = (const float*)d_in[9];
    const float* fc3w  = (const float*)d_in[10];
    const float* fc3b  = (const float*)d_in[11];

    float* out_head = (float*)d_out;
    float* attn_out = out_head + 32;

    float* ws = (float*)d_ws;
    const size_t OFF_XR   = 0;
    const size_t OFF_Q    = OFF_XR + 1052672;
    const size_t OFF_K    = OFF_Q + 2097152;
    const size_t OFF_V    = OFF_K + 2097152;
    const size_t OFF_CTX  = OFF_V + 2097152;
    const size_t OFF_WTST = OFF_CTX + 4194304;
    const size_t OFF_P1   = OFF_WTST + 2097152;
    const size_t OFF_H1   = OFF_P1 + 8454144;
    const size_t OFF_P2   = OFF_H1 + 32768;
    const size_t OFF_MB   = OFF_P2 + 1048576;
    const size_t OFF_AVP  = OFF_MB + 262144;
    const size_t OFF_EMBT = OFF_AVP + 65792;
    const size_t OFF_WT   = OFF_EMBT + 2097152;

    __hip_bfloat16* xR   = (__hip_bfloat16*)(ws + OFF_XR);
    __hip_bfloat16* Qb   = (__hip_bfloat16*)(ws + OFF_Q);
    __hip_bfloat16* Kb   = (__hip_bfloat16*)(ws + OFF_K);
    __hip_bfloat16* Vt   = (__hip_bfloat16*)(ws + OFF_V);
    float* ctx   = ws + OFF_CTX;
    __hip_bfloat16* wtsT = (__hip_bfloat16*)(ws + OFF_WTST);
    float* part1 = ws + OFF_P1;
    __hip_bfloat16* h1R  = (__hip_bfloat16*)(ws + OFF_H1);
    float* part2 = ws + OFF_P2;
    unsigned int* mbits = (unsigned int*)(ws + OFF_MB);
    float* avp   = ws + OFF_AVP;
    float* avc   = ws + OFF_AVP + 65536;
    __hip_bfloat16* embT = (__hip_bfloat16*)(ws + OFF_EMBT);
    __hip_bfloat16* WT   = (__hip_bfloat16*)(ws + OFF_WT);

    prep_kernel<<<dim3(34304), 256, 0, stream>>>(amask, mbits, WQ, WK, WV, WT,
                                                 emb, embT, imask, avp, avc);
    proj_mfma<<<dim3(512), 256, 0, stream>>>(emb, WT, Qb, Kb, Vt);
    attn_mfma<<<dim3(32, BH), 256, 0, stream>>>(Qb, Kb, Vt, mbits, attn_out, ctx);
    wts_kernel<<<dim3(B * 8), 256, 0, stream>>>(ctx, imask, wtsT);
    pooled_mfma<<<dim3(4, 4, B), 256, 0, stream>>>(embT, wtsT, xR);
    avg_comb<<<dim3(B), 256, 0, stream>>>(avp, avc, xR);

    fc_mfma<16, CONCAT, 512><<<dim3(8, 128), 256, 0, stream>>>(xR, fc1w, part1, 0);
    fc_mfma<8, CONCAT, 512><<<dim3(8, 1), 256, 0, stream>>>(xR, fc1w, part1, 128);
    fcreduce1<<<dim3(512), 256, 0, stream>>>(part1, fc1b, h1R);

    fc_mfma<4, DFF, 128><<<dim3(8, 16), 256, 0, stream>>>(h1R, fc2w, part2, 0);
    fc23_kernel<<<dim3(B), 256, 0, stream>>>(part2, fc2b, fc3w, fc3b, out_head);
}